// Round 6
// baseline (178.651 us; speedup 1.0000x reference)
//
#include <hip/hip_runtime.h>
#include <hip/hip_fp16.h>

#define Bsz 256
#define Nn  1152
#define Kk  10
#define NT  384      // 6 waves
#define NW  6

#define W_ELEMS (Kk*Nn*128)   // 2949120
#define U_ELEMS (Bsz*Nn*8)    // 2359296

typedef _Float16 v2h __attribute__((ext_vector_type(2)));

__device__ __forceinline__ unsigned pkh2(float x, float y) {
    __half2 h = __floats2half2_rn(x, y);
    return *reinterpret_cast<unsigned*>(&h);
}
__device__ __forceinline__ float2 uph2(unsigned v) {
    __half2 h;
    *reinterpret_cast<unsigned*>(&h) = v;
    return __half22float2(h);
}

#if __has_builtin(__builtin_amdgcn_fdot2)
__device__ __forceinline__ float fdot2u(unsigned a, unsigned b, float c) {
    union { unsigned u; v2h h; } ua, ub;
    ua.u = a; ub.u = b;
    return __builtin_amdgcn_fdot2(ua.h, ub.h, c, false);
}
#else
__device__ __forceinline__ float fdot2u(unsigned a, unsigned b, float c) {
    const float2 fa = uph2(a), fb = uph2(b);
    return c + fa.x * fb.x + fa.y * fb.y;
}
#endif

// Conversion kernel.
// Blocks [0,90): W fp32 -> dot2-packed fp16. Per (k,n,oh) slot: 32 unsigned,
//   slot[i2*8 + o] = half2(W[k][n][2*i2][oh*8+o], W[k][n][2*i2+1][oh*8+o]).
// Blocks [90,1242): u fp32 -> fp16 straight copy (i-pairs naturally adjacent).
__global__ void cvt_kernel(const float* __restrict__ W, const float* __restrict__ u,
                           unsigned* __restrict__ Wp, __half2* __restrict__ uh) {
    if (blockIdx.x < 90) {
        const int idx = blockIdx.x * 256 + threadIdx.x;   // < 23040 = Kk*Nn*2
        const int k  = idx / 2304;
        const int r  = idx - k * 2304;
        const int n  = r >> 1;
        const int oh = r & 1;
        const float* src = W + ((size_t)(k * Nn + n)) * 128 + oh * 8;
        unsigned* dst = Wp + (size_t)idx * 32;
        #pragma unroll
        for (int i2 = 0; i2 < 4; ++i2) {
            const float4 e0 = *(const float4*)(src + (2*i2  )*16);
            const float4 e1 = *(const float4*)(src + (2*i2  )*16 + 4);
            const float4 f0 = *(const float4*)(src + (2*i2+1)*16);
            const float4 f1 = *(const float4*)(src + (2*i2+1)*16 + 4);
            dst[i2*8+0] = pkh2(e0.x, f0.x);
            dst[i2*8+1] = pkh2(e0.y, f0.y);
            dst[i2*8+2] = pkh2(e0.z, f0.z);
            dst[i2*8+3] = pkh2(e0.w, f0.w);
            dst[i2*8+4] = pkh2(e1.x, f1.x);
            dst[i2*8+5] = pkh2(e1.y, f1.y);
            dst[i2*8+6] = pkh2(e1.z, f1.z);
            dst[i2*8+7] = pkh2(e1.w, f1.w);
        }
    } else {
        const int idx = (blockIdx.x - 90) * 256 + threadIdx.x;  // < 294912
        const float4* p = (const float4*)u + (size_t)idx * 2;
        __half2* o = uh + (size_t)idx * 4;
        const float4 a = p[0], b = p[1];
        o[0] = __floats2half2_rn(a.x, a.y);
        o[1] = __floats2half2_rn(a.z, a.w);
        o[2] = __floats2half2_rn(b.x, b.y);
        o[3] = __floats2half2_rn(b.z, b.w);
    }
}

// One block per (b, k); 6 waves; u_hat fp16 in LDS uhS[n*8 + j] (half2 o-pair j).
// ~39.7 KB LDS -> 4 blocks/CU. Phase 1 and a-scan use v_dot2_f32_f16.
// it=0 s-pass fused into phase 1 (fp32 partials + parity shuffle-reduce).
template<bool HALF>
__global__ __launch_bounds__(NT, 6)
void digitcaps_kernel(const float* __restrict__ u32, const float* __restrict__ W32,
                      const __half* __restrict__ uh, const unsigned* __restrict__ Wp,
                      float* __restrict__ out)
{
    const int t    = threadIdx.x;
    const int lane = t & 63;
    const int wav  = t >> 6;
    const int b    = blockIdx.x;     // 0..255
    const int k    = blockIdx.y;     // 0..9

    __shared__ unsigned uhS[Nn * 8];     // 36864 B
    __shared__ __half   cS[Nn];          // 2304 B
    __shared__ float    redS[NW * 17];   // 408 B  [wav][16 s-cols + d]; also max scratch
    __shared__ __align__(16) float vS[16];
    __shared__ float    mS;

    // ---------------- Phase 1: u_hat = u . W, fused it0 s-partials ----------
    {
        const int oh   = t & 1;
        const int nsub = t >> 1;     // 0..191
        float sacc[8];
        #pragma unroll
        for (int o = 0; o < 8; ++o) sacc[o] = 0.f;
        for (int r = 0; r < 6; ++r) {
            const int n = r * 192 + nsub;
            float a0[8];
            #pragma unroll
            for (int o = 0; o < 8; ++o) a0[o] = 0.f;
            if (HALF) {
                // this (k,n,oh) slot = 8 uint4, base = slot_index * 8
                const uint4* wp8 = (const uint4*)Wp
                                 + ((size_t)((k * Nn + n) * 2 + oh)) * 8;
                uint4 wq[8];
                #pragma unroll
                for (int q = 0; q < 8; ++q) wq[q] = wp8[q];
                const uint4 ubv = *(const uint4*)(uh + ((size_t)b * Nn + n) * 8);
                const unsigned* u2v = (const unsigned*)&ubv;  // 4 half2 (i-pairs)
                const unsigned* wz  = (const unsigned*)wq;    // 32 half2
                #pragma unroll
                for (int i2 = 0; i2 < 4; ++i2)
                    #pragma unroll
                    for (int o = 0; o < 8; ++o)
                        a0[o] = fdot2u(u2v[i2], wz[i2*8 + o], a0[o]);
            } else {
                const float4* up = (const float4*)(u32 + ((size_t)b * Nn + n) * 8);
                const float4 x0 = up[0], x1 = up[1];
                float ua[8] = {x0.x,x0.y,x0.z,x0.w, x1.x,x1.y,x1.z,x1.w};
                #pragma unroll
                for (int i = 0; i < 8; ++i) {
                    const float4* wpf = (const float4*)(W32 + ((size_t)k * Nn + n) * 128 + i * 16 + oh * 8);
                    const float4 q0 = wpf[0], q1 = wpf[1];
                    const float wvf[8] = {q0.x,q0.y,q0.z,q0.w, q1.x,q1.y,q1.z,q1.w};
                    #pragma unroll
                    for (int o = 0; o < 8; ++o) a0[o] += ua[i] * wvf[o];
                }
            }
            *(uint4*)&uhS[n * 8 + oh * 4] =
                make_uint4(pkh2(a0[0], a0[1]), pkh2(a0[2], a0[3]),
                           pkh2(a0[4], a0[5]), pkh2(a0[6], a0[7]));
            #pragma unroll
            for (int o = 0; o < 8; ++o) sacc[o] += a0[o];
        }
        // reduce sacc over lanes of same parity (oh preserved)
        #pragma unroll
        for (int off = 2; off <= 32; off <<= 1)
            #pragma unroll
            for (int o = 0; o < 8; ++o) sacc[o] += __shfl_xor(sacc[o], off);
        if (lane < 2) {
            #pragma unroll
            for (int o = 0; o < 8; ++o) redS[wav * 17 + lane * 8 + o] = sacc[o];
        }
    }
    __syncthreads();

    // ---------------- Phase 2: routing ----------------
    float lg[3] = {0.f, 0.f, 0.f};
    unsigned vH[8];
    const int j_s = lane & 7;
    const int g_s = lane >> 3;

    for (int it = 0; it < 3; ++it) {
        if (it > 0) {
            // pack v into half2 regs
            const float4* vp = (const float4*)vS;
            const float4 va = vp[0], vb = vp[1], vc = vp[2], vd = vp[3];
            vH[0] = pkh2(va.x, va.y); vH[1] = pkh2(va.z, va.w);
            vH[2] = pkh2(vb.x, vb.y); vH[3] = pkh2(vb.z, vb.w);
            vH[4] = pkh2(vc.x, vc.y); vH[5] = pkh2(vc.z, vc.w);
            vH[6] = pkh2(vd.x, vd.y); vH[7] = pkh2(vd.z, vd.w);
            // a-scan: rows n = t, t+NT, t+2NT
            #pragma unroll
            for (int r = 0; r < 3; ++r) {
                const int n = t + r * NT;
                const uint4 qa = *(const uint4*)&uhS[n * 8];
                const uint4 qb = *(const uint4*)&uhS[n * 8 + 4];
                const unsigned* pa = (const unsigned*)&qa;
                const unsigned* pb = (const unsigned*)&qb;
                float acc = 0.f;
                #pragma unroll
                for (int j = 0; j < 4; ++j) acc = fdot2u(pa[j], vH[j], acc);
                #pragma unroll
                for (int j = 0; j < 4; ++j) acc = fdot2u(pb[j], vH[4 + j], acc);
                lg[r] += acc;
            }
            // block max
            float m = fmaxf(fmaxf(lg[0], lg[1]), lg[2]);
            #pragma unroll
            for (int off = 1; off <= 32; off <<= 1) m = fmaxf(m, __shfl_xor(m, off));
            if (lane == 0) redS[wav] = m;
            __syncthreads();
            if (t == 0) {
                float mm = redS[0];
                for (int w = 1; w < NW; ++w) mm = fmaxf(mm, redS[w]);
                mS = mm;
            }
            __syncthreads();
            m = mS;
            cS[t]        = __float2half(__expf(lg[0] - m));
            cS[t + NT]   = __float2half(__expf(lg[1] - m));
            cS[t + 2*NT] = __float2half(__expf(lg[2] - m));
            __syncthreads();
            // s-scan: numerator + denominator
            float spx = 0.f, spy = 0.f, dp = 0.f;
            #pragma unroll
            for (int cc = 0; cc < 24; ++cc) {
                const int n = cc * 48 + wav * 8 + g_s;
                const float c = __half2float(cS[n]);
                const float2 f = uph2(uhS[n * 8 + j_s]);
                spx += c * f.x; spy += c * f.y; dp += c;
            }
            #pragma unroll
            for (int off = 8; off <= 32; off <<= 1) {
                spx += __shfl_xor(spx, off);
                spy += __shfl_xor(spy, off);
                dp  += __shfl_xor(dp,  off);
            }
            if (lane < 8) {
                redS[wav * 17 + 2*j_s    ] = spx;
                redS[wav * 17 + 2*j_s + 1] = spy;
            }
            if (lane == 0) redS[wav * 17 + 16] = dp;
            __syncthreads();
        }

        // ---- squash (16 lanes of wave 0) ----
        if (t < 16) {
            float s = 0.f;
            #pragma unroll
            for (int w = 0; w < NW; ++w) s += redS[w * 17 + t];
            float d;
            if (it == 0) d = (float)Nn;
            else {
                d = 0.f;
                #pragma unroll
                for (int w = 0; w < NW; ++w) d += redS[w * 17 + 16];
            }
            s /= d;
            float s2 = s * s;
            #pragma unroll
            for (int off = 1; off <= 8; off <<= 1) s2 += __shfl_xor(s2, off);
            const float scale = (s2 / (1.f + s2)) * rsqrtf(fmaxf(s2, 1e-30f));
            const float v = s * scale;
            vS[t] = v;
            if (it == 2) out[((size_t)k * Bsz + b) * 16 + t] = v;
        }
        __syncthreads();
    }
}

extern "C" void kernel_launch(void* const* d_in, const int* in_sizes, int n_in,
                              void* d_out, int out_size, void* d_ws, size_t ws_size,
                              hipStream_t stream) {
    const float* u = (const float*)d_in[0];
    const float* W = (const float*)d_in[1];
    float* out = (float*)d_out;
    const size_t need = (size_t)(W_ELEMS + U_ELEMS) * sizeof(__half);
    if (ws_size >= need) {
        unsigned* Wp = (unsigned*)d_ws;
        __half* uhp = (__half*)((char*)d_ws + (size_t)W_ELEMS * sizeof(__half));
        cvt_kernel<<<dim3(90 + U_ELEMS / 8 / 256), dim3(256), 0, stream>>>(
            W, u, Wp, (__half2*)uhp);
        digitcaps_kernel<true><<<dim3(Bsz, Kk), dim3(NT), 0, stream>>>(
            nullptr, nullptr, uhp, Wp, out);
    } else {
        digitcaps_kernel<false><<<dim3(Bsz, Kk), dim3(NT), 0, stream>>>(
            u, W, nullptr, nullptr, out);
    }
}

// Round 7
// 178.252 us; speedup vs baseline: 1.0022x; 1.0022x over previous
//
#include <hip/hip_runtime.h>
#include <hip/hip_fp16.h>

#define Bsz 256
#define Nn  1152
#define Kk  10
#define NT  384      // 6 waves
#define NW  6

#define W_ELEMS (Kk*Nn*128)   // 2949120
#define U_ELEMS (Bsz*Nn*8)    // 2359296

typedef _Float16 v2h __attribute__((ext_vector_type(2)));

__device__ __forceinline__ unsigned pkh2(float x, float y) {
    __half2 h = __floats2half2_rn(x, y);
    return *reinterpret_cast<unsigned*>(&h);
}
__device__ __forceinline__ float2 uph2(unsigned v) {
    __half2 h;
    *reinterpret_cast<unsigned*>(&h) = v;
    return __half22float2(h);
}

#if __has_builtin(__builtin_amdgcn_fdot2)
__device__ __forceinline__ float fdot2u(unsigned a, unsigned b, float c) {
    union { unsigned u; v2h h; } ua, ub;
    ua.u = a; ub.u = b;
    return __builtin_amdgcn_fdot2(ua.h, ub.h, c, false);
}
#else
__device__ __forceinline__ float fdot2u(unsigned a, unsigned b, float c) {
    const float2 fa = uph2(a), fb = uph2(b);
    return c + fa.x * fb.x + fa.y * fb.y;
}
#endif

// accumulate 8 outputs for one i-pair: u half2 `uu` against W half2s wa/wb
#define DOT8(uu, wa, wb)                                              \
    a0[0] = fdot2u(uu, wa.x, a0[0]); a0[1] = fdot2u(uu, wa.y, a0[1]); \
    a0[2] = fdot2u(uu, wa.z, a0[2]); a0[3] = fdot2u(uu, wa.w, a0[3]); \
    a0[4] = fdot2u(uu, wb.x, a0[4]); a0[5] = fdot2u(uu, wb.y, a0[5]); \
    a0[6] = fdot2u(uu, wb.z, a0[6]); a0[7] = fdot2u(uu, wb.w, a0[7]);

// Conversion kernel.
// Blocks [0,90): W fp32 -> dot2-packed fp16. Per (k,n,oh) slot: 32 unsigned,
//   slot[i2*8 + o] = half2(W[k][n][2*i2][oh*8+o], W[k][n][2*i2+1][oh*8+o]).
// Blocks [90,1242): u fp32 -> fp16 straight copy (i-pairs naturally adjacent).
__global__ void cvt_kernel(const float* __restrict__ W, const float* __restrict__ u,
                           unsigned* __restrict__ Wp, __half2* __restrict__ uh) {
    if (blockIdx.x < 90) {
        const int idx = blockIdx.x * 256 + threadIdx.x;   // < 23040 = Kk*Nn*2
        const int k  = idx / 2304;
        const int r  = idx - k * 2304;
        const int n  = r >> 1;
        const int oh = r & 1;
        const float* src = W + ((size_t)(k * Nn + n)) * 128 + oh * 8;
        unsigned* dst = Wp + (size_t)idx * 32;
        #pragma unroll
        for (int i2 = 0; i2 < 4; ++i2) {
            const float4 e0 = *(const float4*)(src + (2*i2  )*16);
            const float4 e1 = *(const float4*)(src + (2*i2  )*16 + 4);
            const float4 f0 = *(const float4*)(src + (2*i2+1)*16);
            const float4 f1 = *(const float4*)(src + (2*i2+1)*16 + 4);
            dst[i2*8+0] = pkh2(e0.x, f0.x);
            dst[i2*8+1] = pkh2(e0.y, f0.y);
            dst[i2*8+2] = pkh2(e0.z, f0.z);
            dst[i2*8+3] = pkh2(e0.w, f0.w);
            dst[i2*8+4] = pkh2(e1.x, f1.x);
            dst[i2*8+5] = pkh2(e1.y, f1.y);
            dst[i2*8+6] = pkh2(e1.z, f1.z);
            dst[i2*8+7] = pkh2(e1.w, f1.w);
        }
    } else {
        const int idx = (blockIdx.x - 90) * 256 + threadIdx.x;  // < 294912
        const float4* p = (const float4*)u + (size_t)idx * 2;
        __half2* o = uh + (size_t)idx * 4;
        const float4 a = p[0], b = p[1];
        o[0] = __floats2half2_rn(a.x, a.y);
        o[1] = __floats2half2_rn(a.z, a.w);
        o[2] = __floats2half2_rn(b.x, b.y);
        o[3] = __floats2half2_rn(b.z, b.w);
    }
}

// One block per (b, k); 6 waves; u_hat fp16 in LDS uhS[n*8 + j] (half2 o-pair j).
// ~39.7 KB LDS -> 4 blocks/CU. Phase 1 and a-scan use v_dot2_f32_f16.
// All W/u/uhS register data held in NAMED uint4 scalars (no address-taken
// private arrays -> no SROA failure -> no scratch spills; round-6 lesson).
template<bool HALF>
__global__ __launch_bounds__(NT, 6)
void digitcaps_kernel(const float* __restrict__ u32, const float* __restrict__ W32,
                      const __half* __restrict__ uh, const unsigned* __restrict__ Wp,
                      float* __restrict__ out)
{
    const int t    = threadIdx.x;
    const int lane = t & 63;
    const int wav  = t >> 6;
    const int b    = blockIdx.x;     // 0..255
    const int k    = blockIdx.y;     // 0..9

    __shared__ unsigned uhS[Nn * 8];     // 36864 B
    __shared__ __half   cS[Nn];          // 2304 B
    __shared__ float    redS[NW * 17];   // 408 B  [wav][16 s-cols + d]; also max scratch
    __shared__ __align__(16) float vS[16];
    __shared__ float    mS;

    // ---------------- Phase 1: u_hat = u . W, fused it0 s-partials ----------
    {
        const int oh   = t & 1;
        const int nsub = t >> 1;     // 0..191
        float sacc[8];
        #pragma unroll
        for (int o = 0; o < 8; ++o) sacc[o] = 0.f;
        for (int r = 0; r < 6; ++r) {
            const int n = r * 192 + nsub;
            float a0[8];
            #pragma unroll
            for (int o = 0; o < 8; ++o) a0[o] = 0.f;
            if (HALF) {
                const uint4* wp8 = (const uint4*)Wp
                                 + ((size_t)((k * Nn + n) * 2 + oh)) * 8;
                const uint4 w0 = wp8[0], w1 = wp8[1], w2 = wp8[2], w3 = wp8[3];
                const uint4 w4 = wp8[4], w5 = wp8[5], w6 = wp8[6], w7 = wp8[7];
                const uint4 uv = *(const uint4*)(uh + ((size_t)b * Nn + n) * 8);
                DOT8(uv.x, w0, w1);   // i-pair 0
                DOT8(uv.y, w2, w3);   // i-pair 1
                DOT8(uv.z, w4, w5);   // i-pair 2
                DOT8(uv.w, w6, w7);   // i-pair 3
            } else {
                const float4* up = (const float4*)(u32 + ((size_t)b * Nn + n) * 8);
                const float4 x0 = up[0], x1 = up[1];
                float ua[8] = {x0.x,x0.y,x0.z,x0.w, x1.x,x1.y,x1.z,x1.w};
                #pragma unroll
                for (int i = 0; i < 8; ++i) {
                    const float4* wpf = (const float4*)(W32 + ((size_t)k * Nn + n) * 128 + i * 16 + oh * 8);
                    const float4 q0 = wpf[0], q1 = wpf[1];
                    a0[0] += ua[i] * q0.x; a0[1] += ua[i] * q0.y;
                    a0[2] += ua[i] * q0.z; a0[3] += ua[i] * q0.w;
                    a0[4] += ua[i] * q1.x; a0[5] += ua[i] * q1.y;
                    a0[6] += ua[i] * q1.z; a0[7] += ua[i] * q1.w;
                }
            }
            *(uint4*)&uhS[n * 8 + oh * 4] =
                make_uint4(pkh2(a0[0], a0[1]), pkh2(a0[2], a0[3]),
                           pkh2(a0[4], a0[5]), pkh2(a0[6], a0[7]));
            #pragma unroll
            for (int o = 0; o < 8; ++o) sacc[o] += a0[o];
        }
        // reduce sacc over lanes of same parity (oh preserved)
        #pragma unroll
        for (int off = 2; off <= 32; off <<= 1)
            #pragma unroll
            for (int o = 0; o < 8; ++o) sacc[o] += __shfl_xor(sacc[o], off);
        if (lane < 2) {
            #pragma unroll
            for (int o = 0; o < 8; ++o) redS[wav * 17 + lane * 8 + o] = sacc[o];
        }
    }
    __syncthreads();

    // ---------------- Phase 2: routing ----------------
    float lg[3] = {0.f, 0.f, 0.f};
    unsigned vH[8];
    const int j_s = lane & 7;
    const int g_s = lane >> 3;

    for (int it = 0; it < 3; ++it) {
        if (it > 0) {
            // pack v into half2 regs
            const float4* vp = (const float4*)vS;
            const float4 va = vp[0], vb = vp[1], vc = vp[2], vd = vp[3];
            vH[0] = pkh2(va.x, va.y); vH[1] = pkh2(va.z, va.w);
            vH[2] = pkh2(vb.x, vb.y); vH[3] = pkh2(vb.z, vb.w);
            vH[4] = pkh2(vc.x, vc.y); vH[5] = pkh2(vc.z, vc.w);
            vH[6] = pkh2(vd.x, vd.y); vH[7] = pkh2(vd.z, vd.w);
            // a-scan: rows n = t, t+NT, t+2NT
            #pragma unroll
            for (int r = 0; r < 3; ++r) {
                const int n = t + r * NT;
                const uint4 qa = *(const uint4*)&uhS[n * 8];
                const uint4 qb = *(const uint4*)&uhS[n * 8 + 4];
                float acc;
                acc = fdot2u(qa.x, vH[0], 0.f);
                acc = fdot2u(qa.y, vH[1], acc);
                acc = fdot2u(qa.z, vH[2], acc);
                acc = fdot2u(qa.w, vH[3], acc);
                acc = fdot2u(qb.x, vH[4], acc);
                acc = fdot2u(qb.y, vH[5], acc);
                acc = fdot2u(qb.z, vH[6], acc);
                acc = fdot2u(qb.w, vH[7], acc);
                lg[r] += acc;
            }
            // block max
            float m = fmaxf(fmaxf(lg[0], lg[1]), lg[2]);
            #pragma unroll
            for (int off = 1; off <= 32; off <<= 1) m = fmaxf(m, __shfl_xor(m, off));
            if (lane == 0) redS[wav] = m;
            __syncthreads();
            if (t == 0) {
                float mm = redS[0];
                for (int w = 1; w < NW; ++w) mm = fmaxf(mm, redS[w]);
                mS = mm;
            }
            __syncthreads();
            m = mS;
            cS[t]        = __float2half(__expf(lg[0] - m));
            cS[t + NT]   = __float2half(__expf(lg[1] - m));
            cS[t + 2*NT] = __float2half(__expf(lg[2] - m));
            __syncthreads();
            // s-scan: numerator + denominator
            float spx = 0.f, spy = 0.f, dp = 0.f;
            #pragma unroll
            for (int cc = 0; cc < 24; ++cc) {
                const int n = cc * 48 + wav * 8 + g_s;
                const float c = __half2float(cS[n]);
                const float2 f = uph2(uhS[n * 8 + j_s]);
                spx += c * f.x; spy += c * f.y; dp += c;
            }
            #pragma unroll
            for (int off = 8; off <= 32; off <<= 1) {
                spx += __shfl_xor(spx, off);
                spy += __shfl_xor(spy, off);
                dp  += __shfl_xor(dp,  off);
            }
            if (lane < 8) {
                redS[wav * 17 + 2*j_s    ] = spx;
                redS[wav * 17 + 2*j_s + 1] = spy;
            }
            if (lane == 0) redS[wav * 17 + 16] = dp;
            __syncthreads();
        }

        // ---- squash (16 lanes of wave 0) ----
        if (t < 16) {
            float s = 0.f;
            #pragma unroll
            for (int w = 0; w < NW; ++w) s += redS[w * 17 + t];
            float d;
            if (it == 0) d = (float)Nn;
            else {
                d = 0.f;
                #pragma unroll
                for (int w = 0; w < NW; ++w) d += redS[w * 17 + 16];
            }
            s /= d;
            float s2 = s * s;
            #pragma unroll
            for (int off = 1; off <= 8; off <<= 1) s2 += __shfl_xor(s2, off);
            const float scale = (s2 / (1.f + s2)) * rsqrtf(fmaxf(s2, 1e-30f));
            const float v = s * scale;
            vS[t] = v;
            if (it == 2) out[((size_t)k * Bsz + b) * 16 + t] = v;
        }
        __syncthreads();
    }
}

extern "C" void kernel_launch(void* const* d_in, const int* in_sizes, int n_in,
                              void* d_out, int out_size, void* d_ws, size_t ws_size,
                              hipStream_t stream) {
    const float* u = (const float*)d_in[0];
    const float* W = (const float*)d_in[1];
    float* out = (float*)d_out;
    const size_t need = (size_t)(W_ELEMS + U_ELEMS) * sizeof(__half);
    if (ws_size >= need) {
        unsigned* Wp = (unsigned*)d_ws;
        __half* uhp = (__half*)((char*)d_ws + (size_t)W_ELEMS * sizeof(__half));
        cvt_kernel<<<dim3(90 + U_ELEMS / 8 / 256), dim3(256), 0, stream>>>(
            W, u, Wp, (__half2*)uhp);
        digitcaps_kernel<true><<<dim3(Bsz, Kk), dim3(NT), 0, stream>>>(
            nullptr, nullptr, uhp, Wp, out);
    } else {
        digitcaps_kernel<false><<<dim3(Bsz, Kk), dim3(NT), 0, stream>>>(
            u, W, nullptr, nullptr, out);
    }
}

// Round 8
// 177.833 us; speedup vs baseline: 1.0046x; 1.0024x over previous
//
#include <hip/hip_runtime.h>
#include <hip/hip_fp16.h>

#define Bsz 256
#define Nn  1152
#define Kk  10
#define NT  384      // 6 waves
#define NW  6

#define W_ELEMS (Kk*Nn*128)   // 2949120
#define U_ELEMS (Bsz*Nn*8)    // 2359296

typedef _Float16 v2h __attribute__((ext_vector_type(2)));

__device__ __forceinline__ unsigned pkh2(float x, float y) {
    return __builtin_bit_cast(unsigned, __floats2half2_rn(x, y));
}
__device__ __forceinline__ float2 uph2(unsigned v) {
    return __half22float2(__builtin_bit_cast(__half2, v));
}

#if __has_builtin(__builtin_amdgcn_fdot2)
__device__ __forceinline__ float fdot2u(unsigned a, unsigned b, float c) {
    return __builtin_amdgcn_fdot2(__builtin_bit_cast(v2h, a),
                                  __builtin_bit_cast(v2h, b), c, false);
}
#else
__device__ __forceinline__ float fdot2u(unsigned a, unsigned b, float c) {
    const float2 fa = uph2(a), fb = uph2(b);
    return c + fa.x * fb.x + fa.y * fb.y;
}
#endif

// accumulate 8 outputs for one i-pair: u half2 `uu` against W half2s wa/wb
#define DOT8(uu, wa, wb)                                              \
    a0[0] = fdot2u(uu, wa.x, a0[0]); a0[1] = fdot2u(uu, wa.y, a0[1]); \
    a0[2] = fdot2u(uu, wa.z, a0[2]); a0[3] = fdot2u(uu, wa.w, a0[3]); \
    a0[4] = fdot2u(uu, wb.x, a0[4]); a0[5] = fdot2u(uu, wb.y, a0[5]); \
    a0[6] = fdot2u(uu, wb.z, a0[6]); a0[7] = fdot2u(uu, wb.w, a0[7]);

// Conversion kernel.
// Blocks [0,90): W fp32 -> dot2-packed fp16. Per (k,n,oh) slot: 32 unsigned,
//   slot[i2*8 + o] = half2(W[k][n][2*i2][oh*8+o], W[k][n][2*i2+1][oh*8+o]).
// Blocks [90,1242): u fp32 -> fp16 straight copy (i-pairs naturally adjacent).
__global__ void cvt_kernel(const float* __restrict__ W, const float* __restrict__ u,
                           unsigned* __restrict__ Wp, __half2* __restrict__ uh) {
    if (blockIdx.x < 90) {
        const int idx = blockIdx.x * 256 + threadIdx.x;   // < 23040 = Kk*Nn*2
        const int k  = idx / 2304;
        const int r  = idx - k * 2304;
        const int n  = r >> 1;
        const int oh = r & 1;
        const float* src = W + ((size_t)(k * Nn + n)) * 128 + oh * 8;
        unsigned* dst = Wp + (size_t)idx * 32;
        #pragma unroll
        for (int i2 = 0; i2 < 4; ++i2) {
            const float4 e0 = *(const float4*)(src + (2*i2  )*16);
            const float4 e1 = *(const float4*)(src + (2*i2  )*16 + 4);
            const float4 f0 = *(const float4*)(src + (2*i2+1)*16);
            const float4 f1 = *(const float4*)(src + (2*i2+1)*16 + 4);
            dst[i2*8+0] = pkh2(e0.x, f0.x);
            dst[i2*8+1] = pkh2(e0.y, f0.y);
            dst[i2*8+2] = pkh2(e0.z, f0.z);
            dst[i2*8+3] = pkh2(e0.w, f0.w);
            dst[i2*8+4] = pkh2(e1.x, f1.x);
            dst[i2*8+5] = pkh2(e1.y, f1.y);
            dst[i2*8+6] = pkh2(e1.z, f1.z);
            dst[i2*8+7] = pkh2(e1.w, f1.w);
        }
    } else {
        const int idx = (blockIdx.x - 90) * 256 + threadIdx.x;  // < 294912
        const float4* p = (const float4*)u + (size_t)idx * 2;
        __half2* o = uh + (size_t)idx * 4;
        const float4 a = p[0], b = p[1];
        o[0] = __floats2half2_rn(a.x, a.y);
        o[1] = __floats2half2_rn(a.z, a.w);
        o[2] = __floats2half2_rn(b.x, b.y);
        o[3] = __floats2half2_rn(b.z, b.w);
    }
}

// One block per (b, k); 6 waves; u_hat fp16 in LDS uhS[n*8 + j] (half2 o-pair j).
// ~39.7 KB LDS -> 4 blocks/CU. v_dot2_f32_f16 everywhere; W loads pipelined
// two uint4-pairs in flight to keep live set <= ~40 VGPRs (spill-free zone).
template<bool HALF>
__global__ __launch_bounds__(NT, 6)
void digitcaps_kernel(const float* __restrict__ u32, const float* __restrict__ W32,
                      const __half* __restrict__ uh, const unsigned* __restrict__ Wp,
                      float* __restrict__ out)
{
    const int t    = threadIdx.x;
    const int lane = t & 63;
    const int wav  = t >> 6;
    const int b    = blockIdx.x;     // 0..255
    const int k    = blockIdx.y;     // 0..9

    __shared__ unsigned uhS[Nn * 8];     // 36864 B
    __shared__ __half   cS[Nn];          // 2304 B
    __shared__ float    redS[NW * 17];   // 408 B  [wav][16 s-cols + d]; also max scratch
    __shared__ __align__(16) float vS[16];
    __shared__ float    mS;

    // ---------------- Phase 1: u_hat = u . W, fused it0 s-partials ----------
    {
        const int oh   = t & 1;
        const int nsub = t >> 1;     // 0..191
        float sacc[8];
        #pragma unroll
        for (int o = 0; o < 8; ++o) sacc[o] = 0.f;
        for (int r = 0; r < 6; ++r) {
            const int n = r * 192 + nsub;
            float a0[8];
            #pragma unroll
            for (int o = 0; o < 8; ++o) a0[o] = 0.f;
            if (HALF) {
                const uint4* wp8 = (const uint4*)Wp
                                 + ((size_t)((k * Nn + n) * 2 + oh)) * 8;
                const uint4 uv = *(const uint4*)(uh + ((size_t)b * Nn + n) * 8);
                // two i2-pairs in flight: ILP without blowing the live set
                uint4 wa0 = wp8[0], wb0 = wp8[1];
                uint4 wa1 = wp8[2], wb1 = wp8[3];
                DOT8(uv.x, wa0, wb0);         // i-pair 0
                wa0 = wp8[4]; wb0 = wp8[5];
                DOT8(uv.y, wa1, wb1);         // i-pair 1
                wa1 = wp8[6]; wb1 = wp8[7];
                DOT8(uv.z, wa0, wb0);         // i-pair 2
                DOT8(uv.w, wa1, wb1);         // i-pair 3
            } else {
                const float4* up = (const float4*)(u32 + ((size_t)b * Nn + n) * 8);
                const float4 x0 = up[0], x1 = up[1];
                float ua[8] = {x0.x,x0.y,x0.z,x0.w, x1.x,x1.y,x1.z,x1.w};
                #pragma unroll
                for (int i = 0; i < 8; ++i) {
                    const float4* wpf = (const float4*)(W32 + ((size_t)k * Nn + n) * 128 + i * 16 + oh * 8);
                    const float4 q0 = wpf[0], q1 = wpf[1];
                    a0[0] += ua[i] * q0.x; a0[1] += ua[i] * q0.y;
                    a0[2] += ua[i] * q0.z; a0[3] += ua[i] * q0.w;
                    a0[4] += ua[i] * q1.x; a0[5] += ua[i] * q1.y;
                    a0[6] += ua[i] * q1.z; a0[7] += ua[i] * q1.w;
                }
            }
            *(uint4*)&uhS[n * 8 + oh * 4] =
                make_uint4(pkh2(a0[0], a0[1]), pkh2(a0[2], a0[3]),
                           pkh2(a0[4], a0[5]), pkh2(a0[6], a0[7]));
            #pragma unroll
            for (int o = 0; o < 8; ++o) sacc[o] += a0[o];
        }
        // reduce sacc over lanes of same parity (oh preserved)
        #pragma unroll
        for (int off = 2; off <= 32; off <<= 1)
            #pragma unroll
            for (int o = 0; o < 8; ++o) sacc[o] += __shfl_xor(sacc[o], off);
        if (lane < 2) {
            #pragma unroll
            for (int o = 0; o < 8; ++o) redS[wav * 17 + lane * 8 + o] = sacc[o];
        }
    }
    __syncthreads();

    // ---------------- Phase 2: routing ----------------
    float lg[3] = {0.f, 0.f, 0.f};
    const int j_s = lane & 7;
    const int g_s = lane >> 3;

    for (int it = 0; it < 3; ++it) {
        if (it > 0) {
            // pack v into half2 named regs
            const float4* vp = (const float4*)vS;
            const float4 va = vp[0], vb = vp[1], vc = vp[2], vd = vp[3];
            const unsigned vh0 = pkh2(va.x, va.y), vh1 = pkh2(va.z, va.w);
            const unsigned vh2 = pkh2(vb.x, vb.y), vh3 = pkh2(vb.z, vb.w);
            const unsigned vh4 = pkh2(vc.x, vc.y), vh5 = pkh2(vc.z, vc.w);
            const unsigned vh6 = pkh2(vd.x, vd.y), vh7 = pkh2(vd.z, vd.w);
            // a-scan: rows n = t, t+NT, t+2NT
            #pragma unroll
            for (int r = 0; r < 3; ++r) {
                const int n = t + r * NT;
                const uint4 qa = *(const uint4*)&uhS[n * 8];
                const uint4 qb = *(const uint4*)&uhS[n * 8 + 4];
                float acc;
                acc = fdot2u(qa.x, vh0, 0.f);
                acc = fdot2u(qa.y, vh1, acc);
                acc = fdot2u(qa.z, vh2, acc);
                acc = fdot2u(qa.w, vh3, acc);
                acc = fdot2u(qb.x, vh4, acc);
                acc = fdot2u(qb.y, vh5, acc);
                acc = fdot2u(qb.z, vh6, acc);
                acc = fdot2u(qb.w, vh7, acc);
                lg[r] += acc;
            }
            // block max
            float m = fmaxf(fmaxf(lg[0], lg[1]), lg[2]);
            #pragma unroll
            for (int off = 1; off <= 32; off <<= 1) m = fmaxf(m, __shfl_xor(m, off));
            if (lane == 0) redS[wav] = m;
            __syncthreads();
            if (t == 0) {
                float mm = redS[0];
                for (int w = 1; w < NW; ++w) mm = fmaxf(mm, redS[w]);
                mS = mm;
            }
            __syncthreads();
            m = mS;
            cS[t]        = __float2half(__expf(lg[0] - m));
            cS[t + NT]   = __float2half(__expf(lg[1] - m));
            cS[t + 2*NT] = __float2half(__expf(lg[2] - m));
            __syncthreads();
            // s-scan: numerator + denominator
            float spx = 0.f, spy = 0.f, dp = 0.f;
            #pragma unroll
            for (int cc = 0; cc < 24; ++cc) {
                const int n = cc * 48 + wav * 8 + g_s;
                const float c = __half2float(cS[n]);
                const float2 f = uph2(uhS[n * 8 + j_s]);
                spx += c * f.x; spy += c * f.y; dp += c;
            }
            #pragma unroll
            for (int off = 8; off <= 32; off <<= 1) {
                spx += __shfl_xor(spx, off);
                spy += __shfl_xor(spy, off);
                dp  += __shfl_xor(dp,  off);
            }
            if (lane < 8) {
                redS[wav * 17 + 2*j_s    ] = spx;
                redS[wav * 17 + 2*j_s + 1] = spy;
            }
            if (lane == 0) redS[wav * 17 + 16] = dp;
            __syncthreads();
        }

        // ---- squash (16 lanes of wave 0) ----
        if (t < 16) {
            float s = 0.f;
            #pragma unroll
            for (int w = 0; w < NW; ++w) s += redS[w * 17 + t];
            float d;
            if (it == 0) d = (float)Nn;
            else {
                d = 0.f;
                #pragma unroll
                for (int w = 0; w < NW; ++w) d += redS[w * 17 + 16];
            }
            s /= d;
            float s2 = s * s;
            #pragma unroll
            for (int off = 1; off <= 8; off <<= 1) s2 += __shfl_xor(s2, off);
            const float scale = (s2 / (1.f + s2)) * rsqrtf(fmaxf(s2, 1e-30f));
            const float v = s * scale;
            vS[t] = v;
            if (it == 2) out[((size_t)k * Bsz + b) * 16 + t] = v;
        }
        __syncthreads();
    }
}

extern "C" void kernel_launch(void* const* d_in, const int* in_sizes, int n_in,
                              void* d_out, int out_size, void* d_ws, size_t ws_size,
                              hipStream_t stream) {
    const float* u = (const float*)d_in[0];
    const float* W = (const float*)d_in[1];
    float* out = (float*)d_out;
    const size_t need = (size_t)(W_ELEMS + U_ELEMS) * sizeof(__half);
    if (ws_size >= need) {
        unsigned* Wp = (unsigned*)d_ws;
        __half* uhp = (__half*)((char*)d_ws + (size_t)W_ELEMS * sizeof(__half));
        cvt_kernel<<<dim3(90 + U_ELEMS / 8 / 256), dim3(256), 0, stream>>>(
            W, u, Wp, (__half2*)uhp);
        digitcaps_kernel<true><<<dim3(Bsz, Kk), dim3(NT), 0, stream>>>(
            nullptr, nullptr, uhp, Wp, out);
    } else {
        digitcaps_kernel<false><<<dim3(Bsz, Kk), dim3(NT), 0, stream>>>(
            u, W, nullptr, nullptr, out);
    }
}